// Round 12
// baseline (8966.175 us; speedup 1.0000x reference)
//
#include <hip/hip_runtime.h>
#include <hip/hip_bf16.h>

typedef float f32x16 __attribute__((ext_vector_type(16)));
typedef unsigned int u32;
typedef unsigned short u16;

#define DT 0.01f

// sin(x) with Cody-Waite reduction mod pi, accurate to ~2e-7 for |x| < ~6000.
__device__ __forceinline__ float fast_sin(float x) {
  const float INVPI = 0.3183098861837907f;
  float n = rintf(x * INVPI);
  int ni = (int)n;
  float r = fmaf(n, -3.140625f, x);          // n*3.140625 exact for |n| < 2^12
  r = fmaf(n, -9.6765358979e-4f, r);         // pi - 3.140625
  float s = r * r;
  float p = fmaf(s, -2.5052108e-8f, 2.7557319e-6f);
  p = fmaf(s, p, -1.9841270e-4f);
  p = fmaf(s, p, 8.3333333e-3f);
  p = fmaf(s, p, -1.6666667e-1f);
  float res = fmaf(r * s, p, r);             // sin(r), |r| <= pi/2
  return (ni & 1) ? -res : res;              // sin(x) = (-1)^n sin(r)
}

// 4x s_load_dwordx16 from a wave-uniform address + waitcnt, all in one asm
// block. Outputs live in SGPRs; consuming FMAs read them as the free scalar
// operand of v_fmac_f32.
__device__ __forceinline__ void sload4(const float* p, f32x16& a, f32x16& b,
                                       f32x16& c, f32x16& d) {
  asm volatile(
      "s_load_dwordx16 %0, %4, 0\n\t"
      "s_load_dwordx16 %1, %4, 0x40\n\t"
      "s_load_dwordx16 %2, %4, 0x80\n\t"
      "s_load_dwordx16 %3, %4, 0xc0\n\t"
      "s_waitcnt lgkmcnt(0)"
      : "=s"(a), "=s"(b), "=s"(c), "=s"(d)
      : "s"(p));
}

// K0s[h,j] = sum_m k0[h,m,j]   (k0: [128,512,512])
__global__ __launch_bounds__(256) void kPrep1(const float* __restrict__ k0,
                                              float* __restrict__ K0s) {
  int t = blockIdx.x * 256 + threadIdx.x;     // 65536 threads
  int h = t >> 9, j = t & 511;
  const float* p = k0 + (size_t)h * 262144 + j;
  float s = 0.f;
  for (int m = 0; m < 512; ++m) s += p[(size_t)m * 512];
  K0s[t] = s;
}

// K1s[h,j] = sum_m k1[h,m,j]   (k1: [128,512,128])
__global__ __launch_bounds__(256) void kPrep2(const float* __restrict__ k1,
                                              float* __restrict__ K1s) {
  int t = blockIdx.x * 256 + threadIdx.x;     // 16384 threads
  int h = t >> 7, j = t & 127;
  const float* p = k1 + (size_t)h * 65536 + j;
  float s = 0.f;
  for (int m = 0; m < 512; ++m) s += p[(size_t)m * 128];
  K1s[t] = s;
}

// M[l,j] = sum_h K1s[l,h] * K0s[h,j]   ([128,512] = K1s @ K0s)
__global__ __launch_bounds__(256) void kPrep3(const float* __restrict__ K0s,
                                              const float* __restrict__ K1s,
                                              float* __restrict__ M) {
  int t = blockIdx.x * 256 + threadIdx.x;     // 65536 threads
  int l = t >> 9, j = t & 511;
  float s = 0.f;
#pragma unroll 8
  for (int h = 0; h < 128; ++h) s = fmaf(K1s[l * 128 + h], K0s[h * 512 + j], s);
  M[t] = s;
}

// Per-row int16 quantization of k2 (row-major kq): 16 threads per row
// (8 elems each), row max via 16-lane xor-shuffle, q = rint(k2*32767/max).
__global__ __launch_bounds__(256) void kConvRow(const float* __restrict__ k2,
                                                short* __restrict__ kq,
                                                float* __restrict__ rowinv) {
  const int t = threadIdx.x;
  const int row = blockIdx.x * 16 + (t >> 4);
  const int seg = t & 15;
  const float* src = k2 + (size_t)row * 128 + seg * 8;
  const float4 a = *(const float4*)(src);
  const float4 b = *(const float4*)(src + 4);
  float m = fmaxf(fmaxf(fmaxf(fabsf(a.x), fabsf(a.y)), fmaxf(fabsf(a.z), fabsf(a.w))),
                  fmaxf(fmaxf(fabsf(b.x), fabsf(b.y)), fmaxf(fabsf(b.z), fabsf(b.w))));
#pragma unroll
  for (int off = 8; off > 0; off >>= 1) m = fmaxf(m, __shfl_xor(m, off, 64));
  const float scale = m > 0.f ? 32767.0f / m : 0.f;
  if (seg == 0) rowinv[row] = m > 0.f ? m / 32767.0f : 0.f;
  uint4 o;
  o.x = (u32)(u16)(short)rintf(a.x * scale) | ((u32)(u16)(short)rintf(a.y * scale) << 16);
  o.y = (u32)(u16)(short)rintf(a.z * scale) | ((u32)(u16)(short)rintf(a.w * scale) << 16);
  o.z = (u32)(u16)(short)rintf(b.x * scale) | ((u32)(u16)(short)rintf(b.y * scale) << 16);
  o.w = (u32)(u16)(short)rintf(b.z * scale) | ((u32)(u16)(short)rintf(b.w * scale) << 16);
  *(uint4*)(kq + (size_t)row * 128 + seg * 8) = o;
}

// Kernel A: RK4 bookkeeping + s2T = transpose(M * y_stage).
__global__ __launch_bounds__(256) void kA(
    const float* __restrict__ y0, const float* __restrict__ bias,
    const float* __restrict__ M, const float* __restrict__ aggp,
    float* __restrict__ ybuf,    // [2][16][512]
    float* __restrict__ racc,    // [16][512]
    float* __restrict__ s2T,     // [128][16]  (j-major, b contiguous)
    float* __restrict__ out,     // [8][16][512]
    int stage, int step) {
  __shared__ float ystage[512];
  __shared__ float red[256];
  const int b = blockIdx.x >> 2, q = blockIdx.x & 3, t = threadIdx.x;
  const float* ycur = ybuf + (step & 1) * 8192;
  float* ynext = ybuf + ((step + 1) & 1) * 8192;

  for (int i = t; i < 512; i += 256) {
    const int idx = b * 512 + i;
    const bool own = (i >> 7) == q;
    float ys;
    if (stage == 0) {
      ys = y0[idx];
      if (own) ynext[idx] = ys;
    } else {
      const float r = bias[idx] - (aggp[idx] + aggp[8192 + idx]);
      const float yb = ycur[idx];
      if (stage == 1) {
        ys = fmaf(0.5f * DT, r, yb);
        if (own) racc[idx] = r;
      } else if (stage == 2) {
        ys = fmaf(0.5f * DT, r, yb);
        if (own) racc[idx] = racc[idx] + 2.f * r;
      } else if (stage == 3) {
        ys = fmaf(DT, r, yb);
        if (own) racc[idx] = racc[idx] + 2.f * r;
      } else {
        ys = yb + (DT / 6.f) * (racc[idx] + r);
        if (own) { ynext[idx] = ys; out[step * 8192 + idx] = ys; }
      }
    }
    ystage[i] = ys;
  }
  __syncthreads();

  const int l = q * 32 + (t >> 3), seg = t & 7;
  const float* Mrow = M + l * 512 + seg * 64;
  float p = 0.f;
#pragma unroll 8
  for (int i = 0; i < 64; ++i) p = fmaf(Mrow[i], ystage[seg * 64 + i], p);
  red[t] = p;
  __syncthreads();
  if (seg == 0) {
    float ssum = 0.f;
#pragma unroll
    for (int k = 0; k < 8; ++k) ssum += red[t + k];
    s2T[l * 16 + b] = ssum;
  }
}

// Kernel B (int16 k2): single-phase wave-private staging, no __syncthreads
// in the main body. Each wave stages its own 64 rows' FULL 128 shorts (16
// batched uint4 loads -> 16 ds_writes), then runs one long pure-compute
// stretch. LDS row stride 136 shorts (272B): granules/row = 17 === 1 mod 8,
// so ds_read_b128 at t*272+qq*16 hits bank-quad (t+qq)%8 — conflict-free.
// 69.9KB LDS -> 2 WGs/CU; latency hidden by the 16-deep in-wave load batch.
__global__ __launch_bounds__(256) void kBi16(
    const short* __restrict__ kq, const float* __restrict__ adj,
    const float* __restrict__ s2T, const float* __restrict__ rowinv,
    float* __restrict__ aggp) {
  __shared__ short lk[256 * 136];   // 69,632 B
  __shared__ float part[64];
  const int t = threadIdx.x;
  const int rid0 = blockIdx.x * 256;
  const int rid = rid0 + t;
  const int l = rid0 >> 9;
  const int half = blockIdx.x & 1;
  const int w = t >> 6, lane = t & 63;

  float dot[16];
#pragma unroll
  for (int b = 0; b < 16; ++b) dot[b] = 0.f;
  float av[16];

  // stage: wave w covers rows [w*64, w*64+64), 16 granules (16B) per row.
  // iteration k: lanes 0..63 -> granules g = k*64+lane; 16-lane clusters
  // each read one full 256B row — coalesced.
#pragma unroll
  for (int k = 0; k < 16; ++k) {
    const int g = k * 64 + lane;
    const int row = w * 64 + (g >> 4), e = g & 15;
    const uint4 v = *(const uint4*)(kq + (size_t)(rid0 + row) * 128 + e * 8);
    *(uint4*)(lk + row * 136 + e * 8) = v;
  }
  // adj prefetch: issued while the LDS writes drain / compute warms up
#pragma unroll
  for (int b = 0; b < 16; ++b) av[b] = adj[(size_t)b * 262144 + rid];

  const short* myrow = lk + t * 136;
#pragma unroll
  for (int qq = 0; qq < 16; ++qq) {
    const uint4 kw = *(const uint4*)(myrow + qq * 8);   // 8 shorts = 8 j
    const int j0 = qq * 8;
    f32x16 sa, sb, sc, sd;
    {
      const float f0 = (float)(short)(kw.x & 0xFFFFu);
      const float f1 = (float)(short)(kw.x >> 16);
      const float f2 = (float)(short)(kw.y & 0xFFFFu);
      const float f3 = (float)(short)(kw.y >> 16);
      sload4(s2T + j0 * 16, sa, sb, sc, sd);
#pragma unroll
      for (int b = 0; b < 16; ++b) dot[b] = fmaf(sa[b], f0, dot[b]);
#pragma unroll
      for (int b = 0; b < 16; ++b) dot[b] = fmaf(sb[b], f1, dot[b]);
#pragma unroll
      for (int b = 0; b < 16; ++b) dot[b] = fmaf(sc[b], f2, dot[b]);
#pragma unroll
      for (int b = 0; b < 16; ++b) dot[b] = fmaf(sd[b], f3, dot[b]);
    }
    {
      const float f4 = (float)(short)(kw.z & 0xFFFFu);
      const float f5 = (float)(short)(kw.z >> 16);
      const float f6 = (float)(short)(kw.w & 0xFFFFu);
      const float f7 = (float)(short)(kw.w >> 16);
      sload4(s2T + (j0 + 4) * 16, sa, sb, sc, sd);
#pragma unroll
      for (int b = 0; b < 16; ++b) dot[b] = fmaf(sa[b], f4, dot[b]);
#pragma unroll
      for (int b = 0; b < 16; ++b) dot[b] = fmaf(sb[b], f5, dot[b]);
#pragma unroll
      for (int b = 0; b < 16; ++b) dot[b] = fmaf(sc[b], f6, dot[b]);
#pragma unroll
      for (int b = 0; b < 16; ++b) dot[b] = fmaf(sd[b], f7, dot[b]);
    }
  }

  const float rinv = rowinv[rid];
#pragma unroll
  for (int b = 0; b < 16; ++b) {
    float v = av[b] * fast_sin(dot[b] * rinv);
#pragma unroll
    for (int off = 32; off > 0; off >>= 1) v += __shfl_down(v, off, 64);
    if ((t & 63) == 0) part[(t >> 6) * 16 + b] = v;
  }
  __syncthreads();
  if (t < 16) {
    float ssum = part[t] + part[16 + t] + part[32 + t] + part[48 + t];
    aggp[half * 8192 + t * 512 + l] = ssum;   // aggp[half][b][l]
  }
}

// Kernel B fallback (fp32 k2, R4 body) — only if ws_size can't hold int16.
__global__ __launch_bounds__(256) void kBf32(
    const float* __restrict__ k2, const float* __restrict__ adj,
    const float* __restrict__ s2T, float* __restrict__ aggp) {
  __shared__ float lk[256 * 36];
  __shared__ float part[64];
  const int t = threadIdx.x;
  const int rid0 = blockIdx.x * 256;
  const int rid = rid0 + t;
  const int l = rid0 >> 9;
  const int half = blockIdx.x & 1;

  float dot[16];
#pragma unroll
  for (int b = 0; b < 16; ++b) dot[b] = 0.f;

  for (int c = 0; c < 4; ++c) {
    __syncthreads();
#pragma unroll
    for (int k = 0; k < 8; ++k) {
      const int f = k * 256 + t, row = f >> 3, e = f & 7;
      const float4 v = *(const float4*)(k2 + (size_t)(rid0 + row) * 128 + c * 32 + e * 4);
      *(float4*)(lk + row * 36 + e * 4) = v;
    }
    __syncthreads();
    const float* myrow = lk + t * 36;
#pragma unroll
    for (int q = 0; q < 8; ++q) {
      const float4 kv = *(const float4*)(myrow + q * 4);
      f32x16 sa, sb, sc, sd;
      sload4(s2T + (c * 32 + q * 4) * 16, sa, sb, sc, sd);
#pragma unroll
      for (int b = 0; b < 16; ++b) dot[b] = fmaf(sa[b], kv.x, dot[b]);
#pragma unroll
      for (int b = 0; b < 16; ++b) dot[b] = fmaf(sb[b], kv.y, dot[b]);
#pragma unroll
      for (int b = 0; b < 16; ++b) dot[b] = fmaf(sc[b], kv.z, dot[b]);
#pragma unroll
      for (int b = 0; b < 16; ++b) dot[b] = fmaf(sd[b], kv.w, dot[b]);
    }
  }

#pragma unroll
  for (int b = 0; b < 16; ++b) {
    float v = adj[(size_t)b * 262144 + rid] * fast_sin(dot[b]);
#pragma unroll
    for (int off = 32; off > 0; off >>= 1) v += __shfl_down(v, off, 64);
    if ((t & 63) == 0) part[(t >> 6) * 16 + b] = v;
  }
  __syncthreads();
  if (t < 16) {
    float ssum = part[t] + part[16 + t] + part[32 + t] + part[48 + t];
    aggp[half * 8192 + t * 512 + l] = ssum;
  }
}

extern "C" void kernel_launch(void* const* d_in, const int* in_sizes, int n_in,
                              void* d_out, int out_size, void* d_ws, size_t ws_size,
                              hipStream_t stream) {
  const float* y0   = (const float*)d_in[0];  // [16,512]
  const float* bias = (const float*)d_in[1];  // [16,512,1]
  const float* adj  = (const float*)d_in[2];  // [16,512,512]
  const float* k0   = (const float*)d_in[3];  // [128,512,512]
  const float* k1   = (const float*)d_in[4];  // [128,512,128]
  const float* k2   = (const float*)d_in[5];  // [512,512,128]
  float* out = (float*)d_out;                 // [8,16,512] f32

  float* w      = (float*)d_ws;
  float* K0s    = w;               // 65536 floats
  float* K1s    = w + 65536;       // 16384
  float* M      = w + 81920;       // 65536
  float* s2T    = w + 147456;      // 2048  ([128][16] transposed)
  float* ybuf   = w + 149504;      // 16384 (2 x 8192, ping-pong)
  float* racc   = w + 165888;      // 8192
  float* aggp   = w + 174080;      // 16384 (2 halves x [16][512])
  float* rowinv = w + 190464;      // 262144 floats = 1 MB
  short* kq     = (short*)(w + 190464 + 262144);  // 33554432 shorts = 64 MB
  const bool useI16 =
      ws_size >= (size_t)(190464 + 262144) * 4 + (size_t)33554432 * 2;

  kPrep1<<<256, 256, 0, stream>>>(k0, K0s);
  kPrep2<<<64, 256, 0, stream>>>(k1, K1s);
  kPrep3<<<256, 256, 0, stream>>>(K0s, K1s, M);
  if (useI16) kConvRow<<<16384, 256, 0, stream>>>(k2, kq, rowinv);

  kA<<<64, 256, 0, stream>>>(y0, bias, M, aggp, ybuf, racc, s2T, out, 0, -1);

  for (int step = 0; step < 8; ++step) {
    for (int stage = 1; stage <= 4; ++stage) {
      if (useI16)
        kBi16<<<1024, 256, 0, stream>>>(kq, adj, s2T, rowinv, aggp);
      else
        kBf32<<<1024, 256, 0, stream>>>(k2, adj, s2T, aggp);
      kA<<<64, 256, 0, stream>>>(y0, bias, M, aggp, ybuf, racc, s2T, out, stage, step);
    }
  }
}

// Round 13
// 1039.172 us; speedup vs baseline: 8.6282x; 8.6282x over previous
//
#include <hip/hip_runtime.h>
#include <hip/hip_bf16.h>

typedef float f32x16 __attribute__((ext_vector_type(16)));
typedef unsigned int u32;
typedef unsigned short u16;

#define DT 0.01f

// sin(x) with Cody-Waite reduction mod pi, accurate to ~2e-7 for |x| < ~6000.
__device__ __forceinline__ float fast_sin(float x) {
  const float INVPI = 0.3183098861837907f;
  float n = rintf(x * INVPI);
  int ni = (int)n;
  float r = fmaf(n, -3.140625f, x);          // n*3.140625 exact for |n| < 2^12
  r = fmaf(n, -9.6765358979e-4f, r);         // pi - 3.140625
  float s = r * r;
  float p = fmaf(s, -2.5052108e-8f, 2.7557319e-6f);
  p = fmaf(s, p, -1.9841270e-4f);
  p = fmaf(s, p, 8.3333333e-3f);
  p = fmaf(s, p, -1.6666667e-1f);
  float res = fmaf(r * s, p, r);             // sin(r), |r| <= pi/2
  return (ni & 1) ? -res : res;              // sin(x) = (-1)^n sin(r)
}

// 4x s_load_dwordx16 from a wave-uniform address + waitcnt, all in one asm
// block. Outputs live in SGPRs; consuming FMAs read them as the free scalar
// operand of v_fmac_f32.
__device__ __forceinline__ void sload4(const float* p, f32x16& a, f32x16& b,
                                       f32x16& c, f32x16& d) {
  asm volatile(
      "s_load_dwordx16 %0, %4, 0\n\t"
      "s_load_dwordx16 %1, %4, 0x40\n\t"
      "s_load_dwordx16 %2, %4, 0x80\n\t"
      "s_load_dwordx16 %3, %4, 0xc0\n\t"
      "s_waitcnt lgkmcnt(0)"
      : "=s"(a), "=s"(b), "=s"(c), "=s"(d)
      : "s"(p));
}

// K0 partial column sums, m split in 2 halves for occupancy (512 WGs vs 256).
// K0p[p][h*512+j] = sum_{m in half p} k0[h,m,j]
__global__ __launch_bounds__(256) void kPrep1(const float* __restrict__ k0,
                                              float* __restrict__ K0p) {
  const int id = (blockIdx.x & 255) * 256 + threadIdx.x;  // 0..65535
  const int p = blockIdx.x >> 8;                          // 0/1
  const int h = id >> 9, j = id & 511;
  const float* q = k0 + (size_t)h * 262144 + (size_t)(p * 256) * 512 + j;
  float s = 0.f;
  for (int m = 0; m < 256; ++m) s += q[(size_t)m * 512];
  K0p[p * 65536 + id] = s;
}

// K1s[h,j] = sum_m k1[h,m,j]   (k1: [128,512,128])
__global__ __launch_bounds__(256) void kPrep2(const float* __restrict__ k1,
                                              float* __restrict__ K1s) {
  int t = blockIdx.x * 256 + threadIdx.x;     // 16384 threads
  int h = t >> 7, j = t & 127;
  const float* p = k1 + (size_t)h * 65536 + j;
  float s = 0.f;
  for (int m = 0; m < 512; ++m) s += p[(size_t)m * 128];
  K1s[t] = s;
}

// M[l,j] = sum_h K1s[l,h] * (K0pA[h,j] + K0pB[h,j])
__global__ __launch_bounds__(256) void kPrep3(const float* __restrict__ K0p,
                                              const float* __restrict__ K1s,
                                              float* __restrict__ M) {
  int t = blockIdx.x * 256 + threadIdx.x;     // 65536 threads
  int l = t >> 9, j = t & 511;
  float s = 0.f;
#pragma unroll 8
  for (int h = 0; h < 128; ++h)
    s = fmaf(K1s[l * 128 + h], K0p[h * 512 + j] + K0p[65536 + h * 512 + j], s);
  M[t] = s;
}

// Per-row int16 quantization of k2 (row-major kq): 16 threads per row
// (8 elems each), row max via 16-lane xor-shuffle, q = rint(k2*32767/max).
__global__ __launch_bounds__(256) void kConvRow(const float* __restrict__ k2,
                                                short* __restrict__ kq,
                                                float* __restrict__ rowinv) {
  const int t = threadIdx.x;
  const int row = blockIdx.x * 16 + (t >> 4);
  const int seg = t & 15;
  const float* src = k2 + (size_t)row * 128 + seg * 8;
  const float4 a = *(const float4*)(src);
  const float4 b = *(const float4*)(src + 4);
  float m = fmaxf(fmaxf(fmaxf(fabsf(a.x), fabsf(a.y)), fmaxf(fabsf(a.z), fabsf(a.w))),
                  fmaxf(fmaxf(fabsf(b.x), fabsf(b.y)), fmaxf(fabsf(b.z), fabsf(b.w))));
#pragma unroll
  for (int off = 8; off > 0; off >>= 1) m = fmaxf(m, __shfl_xor(m, off, 64));
  const float scale = m > 0.f ? 32767.0f / m : 0.f;
  if (seg == 0) rowinv[row] = m > 0.f ? m / 32767.0f : 0.f;
  uint4 o;
  o.x = (u32)(u16)(short)rintf(a.x * scale) | ((u32)(u16)(short)rintf(a.y * scale) << 16);
  o.y = (u32)(u16)(short)rintf(a.z * scale) | ((u32)(u16)(short)rintf(a.w * scale) << 16);
  o.z = (u32)(u16)(short)rintf(b.x * scale) | ((u32)(u16)(short)rintf(b.y * scale) << 16);
  o.w = (u32)(u16)(short)rintf(b.z * scale) | ((u32)(u16)(short)rintf(b.w * scale) << 16);
  *(uint4*)(kq + (size_t)row * 128 + seg * 8) = o;
}

// Kernel A v2: RK4 bookkeeping + s2T = transpose(M * y_stage).
// Re-gridded to 256 WGs (b = blk>>4, l-group lg = blk&15 of 8 l's) so the
// s2 GEMV spreads across the chip (old 64-WG version was latency-bound at
// ~4.3us). Dots use 32-lane groups with bank-rotated LDS reads + shuffle
// reduce. Ownership of y/racc/out writes: chunk (i>>5)==lg (each idx once).
__global__ __launch_bounds__(256) void kA2(
    const float* __restrict__ y0, const float* __restrict__ bias,
    const float* __restrict__ M, const float* __restrict__ aggp,
    float* __restrict__ ybuf,    // [2][16][512]
    float* __restrict__ racc,    // [16][512]
    float* __restrict__ s2T,     // [128][16]  (j-major, b contiguous)
    float* __restrict__ out,     // [8][16][512]
    int stage, int step) {
  __shared__ float ystage[512];
  const int b = blockIdx.x >> 4, lg = blockIdx.x & 15, t = threadIdx.x;
  const float* ycur = ybuf + (step & 1) * 8192;
  float* ynext = ybuf + ((step + 1) & 1) * 8192;

  for (int i = t; i < 512; i += 256) {
    const int idx = b * 512 + i;
    const bool own = (i >> 5) == lg;
    float ys;
    if (stage == 0) {
      ys = y0[idx];
      if (own) ynext[idx] = ys;       // init writes ybuf[0] (step = -1)
    } else {
      const float r = bias[idx] - (aggp[idx] + aggp[8192 + idx]);
      const float yb = ycur[idx];
      if (stage == 1) {
        ys = fmaf(0.5f * DT, r, yb);
        if (own) racc[idx] = r;
      } else if (stage == 2) {
        ys = fmaf(0.5f * DT, r, yb);
        if (own) racc[idx] = racc[idx] + 2.f * r;
      } else if (stage == 3) {
        ys = fmaf(DT, r, yb);
        if (own) racc[idx] = racc[idx] + 2.f * r;
      } else {  // stage 4: finish step
        ys = yb + (DT / 6.f) * (racc[idx] + r);
        if (own) { ynext[idx] = ys; out[step * 8192 + idx] = ys; }
      }
    }
    ystage[i] = ys;
  }
  __syncthreads();

  // 8 dot groups x 32 lanes; lane u covers i in [u*16, u*16+16) with a
  // k-rotated float4 order so LDS banks spread (20u+4k mod 32 distinct).
  const int g = t >> 5, u = t & 31;
  const int l = lg * 8 + g;
  const float* Mrow = M + l * 512;
  const int i0 = u * 16;
  float p = 0.f;
#pragma unroll
  for (int k = 0; k < 4; ++k) {
    const int off = ((u + k) & 3) << 2;
    const float4 mv = *(const float4*)(Mrow + i0 + off);
    const float4 yv = *(const float4*)(ystage + i0 + off);
    p = fmaf(mv.x, yv.x, p);
    p = fmaf(mv.y, yv.y, p);
    p = fmaf(mv.z, yv.z, p);
    p = fmaf(mv.w, yv.w, p);
  }
#pragma unroll
  for (int off = 16; off > 0; off >>= 1) p += __shfl_down(p, off, 32);
  if (u == 0) s2T[l * 16 + b] = p;
}

// Kernel B (int16 k2) — EXACT R11 version (proven ~25us): wave-private
// 2-chunk staging, no __syncthreads in main loop. Wave w stages rows
// [w*64, w*64+64) (one wave-load = 8 full 128B lines) and its own threads
// consume exactly those rows -> ordering via the wave's in-order DS pipe.
// LDS stride 72 shorts (144B) = proven 0-conflict. DO NOT restructure:
// single-phase (R12) and barrier-free-global (R10) variants both ran ~290us.
__global__ __launch_bounds__(256) void kBi16(
    const short* __restrict__ kq, const float* __restrict__ adj,
    const float* __restrict__ s2T, const float* __restrict__ rowinv,
    float* __restrict__ aggp) {
  __shared__ short lk[256 * 72];   // 36,864 B
  __shared__ float part[64];
  const int t = threadIdx.x;
  const int rid0 = blockIdx.x * 256;
  const int rid = rid0 + t;
  const int l = rid0 >> 9;
  const int half = blockIdx.x & 1;
  const int w = t >> 6, lane = t & 63;

  float dot[16];
#pragma unroll
  for (int b = 0; b < 16; ++b) dot[b] = 0.f;
  float av[16];

  for (int c = 0; c < 2; ++c) {    // two 64-j chunks
    // wave-private stage: 8 uint4 per lane covering this wave's 64 rows
#pragma unroll
    for (int k = 0; k < 8; ++k) {
      const int g = k * 64 + lane;               // 0..511
      const int row = w * 64 + (g >> 3), e = g & 7;
      const uint4 v = *(const uint4*)(kq + (size_t)(rid0 + row) * 128 + c * 64 + e * 8);
      *(uint4*)(lk + row * 72 + e * 8) = v;
    }
    if (c == 1) {                  // adj prefetch, in-flight under chunk-1 FMA
#pragma unroll
      for (int b = 0; b < 16; ++b) av[b] = adj[(size_t)b * 262144 + rid];
    }
    const short* myrow = lk + t * 72;
#pragma unroll
    for (int qq = 0; qq < 8; ++qq) {
      const uint4 kw = *(const uint4*)(myrow + qq * 8);   // 8 shorts = 8 j
      const int j0 = c * 64 + qq * 8;
      f32x16 sa, sb, sc, sd;
      {
        const float f0 = (float)(short)(kw.x & 0xFFFFu);
        const float f1 = (float)(short)(kw.x >> 16);
        const float f2 = (float)(short)(kw.y & 0xFFFFu);
        const float f3 = (float)(short)(kw.y >> 16);
        sload4(s2T + j0 * 16, sa, sb, sc, sd);
#pragma unroll
        for (int b = 0; b < 16; ++b) dot[b] = fmaf(sa[b], f0, dot[b]);
#pragma unroll
        for (int b = 0; b < 16; ++b) dot[b] = fmaf(sb[b], f1, dot[b]);
#pragma unroll
        for (int b = 0; b < 16; ++b) dot[b] = fmaf(sc[b], f2, dot[b]);
#pragma unroll
        for (int b = 0; b < 16; ++b) dot[b] = fmaf(sd[b], f3, dot[b]);
      }
      {
        const float f4 = (float)(short)(kw.z & 0xFFFFu);
        const float f5 = (float)(short)(kw.z >> 16);
        const float f6 = (float)(short)(kw.w & 0xFFFFu);
        const float f7 = (float)(short)(kw.w >> 16);
        sload4(s2T + (j0 + 4) * 16, sa, sb, sc, sd);
#pragma unroll
        for (int b = 0; b < 16; ++b) dot[b] = fmaf(sa[b], f4, dot[b]);
#pragma unroll
        for (int b = 0; b < 16; ++b) dot[b] = fmaf(sb[b], f5, dot[b]);
#pragma unroll
        for (int b = 0; b < 16; ++b) dot[b] = fmaf(sc[b], f6, dot[b]);
#pragma unroll
        for (int b = 0; b < 16; ++b) dot[b] = fmaf(sd[b], f7, dot[b]);
      }
    }
  }

  const float rinv = rowinv[rid];
#pragma unroll
  for (int b = 0; b < 16; ++b) {
    float v = av[b] * fast_sin(dot[b] * rinv);
#pragma unroll
    for (int off = 32; off > 0; off >>= 1) v += __shfl_down(v, off, 64);
    if ((t & 63) == 0) part[(t >> 6) * 16 + b] = v;
  }
  __syncthreads();
  if (t < 16) {
    float ssum = part[t] + part[16 + t] + part[32 + t] + part[48 + t];
    aggp[half * 8192 + t * 512 + l] = ssum;   // aggp[half][b][l]
  }
}

// Kernel B fallback (fp32 k2, R4 body) — only if ws_size can't hold int16.
__global__ __launch_bounds__(256) void kBf32(
    const float* __restrict__ k2, const float* __restrict__ adj,
    const float* __restrict__ s2T, float* __restrict__ aggp) {
  __shared__ float lk[256 * 36];
  __shared__ float part[64];
  const int t = threadIdx.x;
  const int rid0 = blockIdx.x * 256;
  const int rid = rid0 + t;
  const int l = rid0 >> 9;
  const int half = blockIdx.x & 1;

  float dot[16];
#pragma unroll
  for (int b = 0; b < 16; ++b) dot[b] = 0.f;

  for (int c = 0; c < 4; ++c) {
    __syncthreads();
#pragma unroll
    for (int k = 0; k < 8; ++k) {
      const int f = k * 256 + t, row = f >> 3, e = f & 7;
      const float4 v = *(const float4*)(k2 + (size_t)(rid0 + row) * 128 + c * 32 + e * 4);
      *(float4*)(lk + row * 36 + e * 4) = v;
    }
    __syncthreads();
    const float* myrow = lk + t * 36;
#pragma unroll
    for (int q = 0; q < 8; ++q) {
      const float4 kv = *(const float4*)(myrow + q * 4);
      f32x16 sa, sb, sc, sd;
      sload4(s2T + (c * 32 + q * 4) * 16, sa, sb, sc, sd);
#pragma unroll
      for (int b = 0; b < 16; ++b) dot[b] = fmaf(sa[b], kv.x, dot[b]);
#pragma unroll
      for (int b = 0; b < 16; ++b) dot[b] = fmaf(sb[b], kv.y, dot[b]);
#pragma unroll
      for (int b = 0; b < 16; ++b) dot[b] = fmaf(sc[b], kv.z, dot[b]);
#pragma unroll
      for (int b = 0; b < 16; ++b) dot[b] = fmaf(sd[b], kv.w, dot[b]);
    }
  }

#pragma unroll
  for (int b = 0; b < 16; ++b) {
    float v = adj[(size_t)b * 262144 + rid] * fast_sin(dot[b]);
#pragma unroll
    for (int off = 32; off > 0; off >>= 1) v += __shfl_down(v, off, 64);
    if ((t & 63) == 0) part[(t >> 6) * 16 + b] = v;
  }
  __syncthreads();
  if (t < 16) {
    float ssum = part[t] + part[16 + t] + part[32 + t] + part[48 + t];
    aggp[half * 8192 + t * 512 + l] = ssum;
  }
}

extern "C" void kernel_launch(void* const* d_in, const int* in_sizes, int n_in,
                              void* d_out, int out_size, void* d_ws, size_t ws_size,
                              hipStream_t stream) {
  const float* y0   = (const float*)d_in[0];  // [16,512]
  const float* bias = (const float*)d_in[1];  // [16,512,1]
  const float* adj  = (const float*)d_in[2];  // [16,512,512]
  const float* k0   = (const float*)d_in[3];  // [128,512,512]
  const float* k1   = (const float*)d_in[4];  // [128,512,128]
  const float* k2   = (const float*)d_in[5];  // [512,512,128]
  float* out = (float*)d_out;                 // [8,16,512] f32

  float* w      = (float*)d_ws;
  float* K0p    = w;               // 131072 floats (2 partials)
  float* K1s    = w + 131072;      // 16384
  float* M      = w + 147456;      // 65536
  float* s2T    = w + 212992;      // 2048  ([128][16] transposed)
  float* ybuf   = w + 215040;      // 16384 (2 x 8192, ping-pong)
  float* racc   = w + 231424;      // 8192
  float* aggp   = w + 239616;      // 16384 (2 halves x [16][512])
  float* rowinv = w + 256000;      // 262144 floats = 1 MB
  short* kq     = (short*)(w + 518144);  // 33554432 shorts = 64 MB
  const bool useI16 =
      ws_size >= (size_t)518144 * 4 + (size_t)33554432 * 2;

  kPrep1<<<512, 256, 0, stream>>>(k0, K0p);
  kPrep2<<<64, 256, 0, stream>>>(k1, K1s);
  kPrep3<<<256, 256, 0, stream>>>(K0p, K1s, M);
  if (useI16) kConvRow<<<16384, 256, 0, stream>>>(k2, kq, rowinv);

  // init: y = y0, s2T = (M*y0)^T  (step = -1 makes ping-pong write ybuf[0])
  kA2<<<256, 256, 0, stream>>>(y0, bias, M, aggp, ybuf, racc, s2T, out, 0, -1);

  for (int step = 0; step < 8; ++step) {
    for (int stage = 1; stage <= 4; ++stage) {
      if (useI16)
        kBi16<<<1024, 256, 0, stream>>>(kq, adj, s2T, rowinv, aggp);
      else
        kBf32<<<1024, 256, 0, stream>>>(k2, adj, s2T, aggp);
      kA2<<<256, 256, 0, stream>>>(y0, bias, M, aggp, ybuf, racc, s2T, out, stage, step);
    }
  }
}

// Round 14
// 1033.301 us; speedup vs baseline: 8.6772x; 1.0057x over previous
//
#include <hip/hip_runtime.h>
#include <hip/hip_bf16.h>

typedef float f32x16 __attribute__((ext_vector_type(16)));
typedef unsigned int u32;
typedef unsigned short u16;

#define DT 0.01f

// sin(x) with Cody-Waite reduction mod pi, accurate to ~2e-7 for |x| < ~6000.
__device__ __forceinline__ float fast_sin(float x) {
  const float INVPI = 0.3183098861837907f;
  float n = rintf(x * INVPI);
  int ni = (int)n;
  float r = fmaf(n, -3.140625f, x);          // n*3.140625 exact for |n| < 2^12
  r = fmaf(n, -9.6765358979e-4f, r);         // pi - 3.140625
  float s = r * r;
  float p = fmaf(s, -2.5052108e-8f, 2.7557319e-6f);
  p = fmaf(s, p, -1.9841270e-4f);
  p = fmaf(s, p, 8.3333333e-3f);
  p = fmaf(s, p, -1.6666667e-1f);
  float res = fmaf(r * s, p, r);             // sin(r), |r| <= pi/2
  return (ni & 1) ? -res : res;              // sin(x) = (-1)^n sin(r)
}

// 4x s_load_dwordx16 from a wave-uniform address + waitcnt, all in one asm
// block. Outputs live in SGPRs; consuming FMAs read them as the free scalar
// operand of v_fmac_f32.
__device__ __forceinline__ void sload4(const float* p, f32x16& a, f32x16& b,
                                       f32x16& c, f32x16& d) {
  asm volatile(
      "s_load_dwordx16 %0, %4, 0\n\t"
      "s_load_dwordx16 %1, %4, 0x40\n\t"
      "s_load_dwordx16 %2, %4, 0x80\n\t"
      "s_load_dwordx16 %3, %4, 0xc0\n\t"
      "s_waitcnt lgkmcnt(0)"
      : "=s"(a), "=s"(b), "=s"(c), "=s"(d)
      : "s"(p));
}

// K0 partial column sums, m split in 2 halves for occupancy (512 WGs vs 256).
// K0p[p][h*512+j] = sum_{m in half p} k0[h,m,j]
__global__ __launch_bounds__(256) void kPrep1(const float* __restrict__ k0,
                                              float* __restrict__ K0p) {
  const int id = (blockIdx.x & 255) * 256 + threadIdx.x;  // 0..65535
  const int p = blockIdx.x >> 8;                          // 0/1
  const int h = id >> 9, j = id & 511;
  const float* q = k0 + (size_t)h * 262144 + (size_t)(p * 256) * 512 + j;
  float s = 0.f;
  for (int m = 0; m < 256; ++m) s += q[(size_t)m * 512];
  K0p[p * 65536 + id] = s;
}

// K1s[h,j] = sum_m k1[h,m,j]   (k1: [128,512,128])
__global__ __launch_bounds__(256) void kPrep2(const float* __restrict__ k1,
                                              float* __restrict__ K1s) {
  int t = blockIdx.x * 256 + threadIdx.x;     // 16384 threads
  int h = t >> 7, j = t & 127;
  const float* p = k1 + (size_t)h * 65536 + j;
  float s = 0.f;
  for (int m = 0; m < 512; ++m) s += p[(size_t)m * 128];
  K1s[t] = s;
}

// M[l,j] = sum_h K1s[l,h] * (K0pA[h,j] + K0pB[h,j])
__global__ __launch_bounds__(256) void kPrep3(const float* __restrict__ K0p,
                                              const float* __restrict__ K1s,
                                              float* __restrict__ M) {
  int t = blockIdx.x * 256 + threadIdx.x;     // 65536 threads
  int l = t >> 9, j = t & 511;
  float s = 0.f;
#pragma unroll 8
  for (int h = 0; h < 128; ++h)
    s = fmaf(K1s[l * 128 + h], K0p[h * 512 + j] + K0p[65536 + h * 512 + j], s);
  M[t] = s;
}

// Per-row int16 quantization of k2 (row-major kq): 16 threads per row
// (8 elems each), row max via 16-lane xor-shuffle, q = rint(k2*32767/max).
__global__ __launch_bounds__(256) void kConvRow(const float* __restrict__ k2,
                                                short* __restrict__ kq,
                                                float* __restrict__ rowinv) {
  const int t = threadIdx.x;
  const int row = blockIdx.x * 16 + (t >> 4);
  const int seg = t & 15;
  const float* src = k2 + (size_t)row * 128 + seg * 8;
  const float4 a = *(const float4*)(src);
  const float4 b = *(const float4*)(src + 4);
  float m = fmaxf(fmaxf(fmaxf(fabsf(a.x), fabsf(a.y)), fmaxf(fabsf(a.z), fabsf(a.w))),
                  fmaxf(fmaxf(fabsf(b.x), fabsf(b.y)), fmaxf(fabsf(b.z), fabsf(b.w))));
#pragma unroll
  for (int off = 8; off > 0; off >>= 1) m = fmaxf(m, __shfl_xor(m, off, 64));
  const float scale = m > 0.f ? 32767.0f / m : 0.f;
  if (seg == 0) rowinv[row] = m > 0.f ? m / 32767.0f : 0.f;
  uint4 o;
  o.x = (u32)(u16)(short)rintf(a.x * scale) | ((u32)(u16)(short)rintf(a.y * scale) << 16);
  o.y = (u32)(u16)(short)rintf(a.z * scale) | ((u32)(u16)(short)rintf(a.w * scale) << 16);
  o.z = (u32)(u16)(short)rintf(b.x * scale) | ((u32)(u16)(short)rintf(b.y * scale) << 16);
  o.w = (u32)(u16)(short)rintf(b.z * scale) | ((u32)(u16)(short)rintf(b.w * scale) << 16);
  *(uint4*)(kq + (size_t)row * 128 + seg * 8) = o;
}

// Kernel A v2: RK4 bookkeeping + s2T = transpose(M * y_stage).
// 256 WGs (b = blk>>4, l-group lg = blk&15 of 8 l's); 32-lane dot groups
// with bank-rotated LDS reads + shuffle reduce.
__global__ __launch_bounds__(256) void kA2(
    const float* __restrict__ y0, const float* __restrict__ bias,
    const float* __restrict__ M, const float* __restrict__ aggp,
    float* __restrict__ ybuf,    // [2][16][512]
    float* __restrict__ racc,    // [16][512]
    float* __restrict__ s2T,     // [128][16]  (j-major, b contiguous)
    float* __restrict__ out,     // [8][16][512]
    int stage, int step) {
  __shared__ float ystage[512];
  const int b = blockIdx.x >> 4, lg = blockIdx.x & 15, t = threadIdx.x;
  const float* ycur = ybuf + (step & 1) * 8192;
  float* ynext = ybuf + ((step + 1) & 1) * 8192;

  for (int i = t; i < 512; i += 256) {
    const int idx = b * 512 + i;
    const bool own = (i >> 5) == lg;
    float ys;
    if (stage == 0) {
      ys = y0[idx];
      if (own) ynext[idx] = ys;       // init writes ybuf[0] (step = -1)
    } else {
      const float r = bias[idx] - (aggp[idx] + aggp[8192 + idx]);
      const float yb = ycur[idx];
      if (stage == 1) {
        ys = fmaf(0.5f * DT, r, yb);
        if (own) racc[idx] = r;
      } else if (stage == 2) {
        ys = fmaf(0.5f * DT, r, yb);
        if (own) racc[idx] = racc[idx] + 2.f * r;
      } else if (stage == 3) {
        ys = fmaf(DT, r, yb);
        if (own) racc[idx] = racc[idx] + 2.f * r;
      } else {  // stage 4: finish step
        ys = yb + (DT / 6.f) * (racc[idx] + r);
        if (own) { ynext[idx] = ys; out[step * 8192 + idx] = ys; }
      }
    }
    ystage[i] = ys;
  }
  __syncthreads();

  const int g = t >> 5, u = t & 31;
  const int l = lg * 8 + g;
  const float* Mrow = M + l * 512;
  const int i0 = u * 16;
  float p = 0.f;
#pragma unroll
  for (int k = 0; k < 4; ++k) {
    const int off = ((u + k) & 3) << 2;
    const float4 mv = *(const float4*)(Mrow + i0 + off);
    const float4 yv = *(const float4*)(ystage + i0 + off);
    p = fmaf(mv.x, yv.x, p);
    p = fmaf(mv.y, yv.y, p);
    p = fmaf(mv.z, yv.z, p);
    p = fmaf(mv.w, yv.w, p);
  }
#pragma unroll
  for (int off = 16; off > 0; off >>= 1) p += __shfl_down(p, off, 32);
  if (u == 0) s2T[l * 16 + b] = p;
}

// Kernel B (int16 k2) — R11 structure (proven ~25us) + rolling kw prefetch:
// read qq+1's uint4 BEFORE qq's sload4 blocks, so the mandatory lgkmcnt(0)
// drain inside sload4 (shared LDS/SMEM counter) doubles as the prefetch
// wait — qq+1's compute starts with kw already in VGPRs, no exposed ds
// latency. FMA order unchanged (bitwise-identical output). DO NOT
// restructure phases: single-phase (R12) and barrier-free-global (R10)
// variants both collapsed to ~290us.
__global__ __launch_bounds__(256) void kBi16(
    const short* __restrict__ kq, const float* __restrict__ adj,
    const float* __restrict__ s2T, const float* __restrict__ rowinv,
    float* __restrict__ aggp) {
  __shared__ short lk[256 * 72];   // 36,864 B
  __shared__ float part[64];
  const int t = threadIdx.x;
  const int rid0 = blockIdx.x * 256;
  const int rid = rid0 + t;
  const int l = rid0 >> 9;
  const int half = blockIdx.x & 1;
  const int w = t >> 6, lane = t & 63;

  float dot[16];
#pragma unroll
  for (int b = 0; b < 16; ++b) dot[b] = 0.f;
  float av[16];
  const float rinv = rowinv[rid];   // issued early, consumed in epilogue

  for (int c = 0; c < 2; ++c) {    // two 64-j chunks
    // wave-private stage: 8 uint4 per lane covering this wave's 64 rows
#pragma unroll
    for (int k = 0; k < 8; ++k) {
      const int g = k * 64 + lane;               // 0..511
      const int row = w * 64 + (g >> 3), e = g & 7;
      const uint4 v = *(const uint4*)(kq + (size_t)(rid0 + row) * 128 + c * 64 + e * 8);
      *(uint4*)(lk + row * 72 + e * 8) = v;
    }
    if (c == 1) {                  // adj prefetch, in-flight under chunk-1 FMA
#pragma unroll
      for (int b = 0; b < 16; ++b) av[b] = adj[(size_t)b * 262144 + rid];
    }
    const short* myrow = lk + t * 72;
    uint4 kw = *(const uint4*)(myrow);            // qq = 0 kw
#pragma unroll
    for (int qq = 0; qq < 8; ++qq) {
      uint4 kwn;
      if (qq < 7) kwn = *(const uint4*)(myrow + (qq + 1) * 8);  // prefetch
      const int j0 = c * 64 + qq * 8;
      f32x16 sa, sb, sc, sd;
      {
        const float f0 = (float)(short)(kw.x & 0xFFFFu);
        const float f1 = (float)(short)(kw.x >> 16);
        const float f2 = (float)(short)(kw.y & 0xFFFFu);
        const float f3 = (float)(short)(kw.y >> 16);
        sload4(s2T + j0 * 16, sa, sb, sc, sd);
#pragma unroll
        for (int b = 0; b < 16; ++b) dot[b] = fmaf(sa[b], f0, dot[b]);
#pragma unroll
        for (int b = 0; b < 16; ++b) dot[b] = fmaf(sb[b], f1, dot[b]);
#pragma unroll
        for (int b = 0; b < 16; ++b) dot[b] = fmaf(sc[b], f2, dot[b]);
#pragma unroll
        for (int b = 0; b < 16; ++b) dot[b] = fmaf(sd[b], f3, dot[b]);
      }
      {
        const float f4 = (float)(short)(kw.z & 0xFFFFu);
        const float f5 = (float)(short)(kw.z >> 16);
        const float f6 = (float)(short)(kw.w & 0xFFFFu);
        const float f7 = (float)(short)(kw.w >> 16);
        sload4(s2T + (j0 + 4) * 16, sa, sb, sc, sd);
#pragma unroll
        for (int b = 0; b < 16; ++b) dot[b] = fmaf(sa[b], f4, dot[b]);
#pragma unroll
        for (int b = 0; b < 16; ++b) dot[b] = fmaf(sb[b], f5, dot[b]);
#pragma unroll
        for (int b = 0; b < 16; ++b) dot[b] = fmaf(sc[b], f6, dot[b]);
#pragma unroll
        for (int b = 0; b < 16; ++b) dot[b] = fmaf(sd[b], f7, dot[b]);
      }
      if (qq < 7) kw = kwn;
    }
  }

#pragma unroll
  for (int b = 0; b < 16; ++b) {
    float v = av[b] * fast_sin(dot[b] * rinv);
#pragma unroll
    for (int off = 32; off > 0; off >>= 1) v += __shfl_down(v, off, 64);
    if ((t & 63) == 0) part[(t >> 6) * 16 + b] = v;
  }
  __syncthreads();
  if (t < 16) {
    float ssum = part[t] + part[16 + t] + part[32 + t] + part[48 + t];
    aggp[half * 8192 + t * 512 + l] = ssum;   // aggp[half][b][l]
  }
}

// Kernel B fallback (fp32 k2, R4 body) — only if ws_size can't hold int16.
__global__ __launch_bounds__(256) void kBf32(
    const float* __restrict__ k2, const float* __restrict__ adj,
    const float* __restrict__ s2T, float* __restrict__ aggp) {
  __shared__ float lk[256 * 36];
  __shared__ float part[64];
  const int t = threadIdx.x;
  const int rid0 = blockIdx.x * 256;
  const int rid = rid0 + t;
  const int l = rid0 >> 9;
  const int half = blockIdx.x & 1;

  float dot[16];
#pragma unroll
  for (int b = 0; b < 16; ++b) dot[b] = 0.f;

  for (int c = 0; c < 4; ++c) {
    __syncthreads();
#pragma unroll
    for (int k = 0; k < 8; ++k) {
      const int f = k * 256 + t, row = f >> 3, e = f & 7;
      const float4 v = *(const float4*)(k2 + (size_t)(rid0 + row) * 128 + c * 32 + e * 4);
      *(float4*)(lk + row * 36 + e * 4) = v;
    }
    __syncthreads();
    const float* myrow = lk + t * 36;
#pragma unroll
    for (int q = 0; q < 8; ++q) {
      const float4 kv = *(const float4*)(myrow + q * 4);
      f32x16 sa, sb, sc, sd;
      sload4(s2T + (c * 32 + q * 4) * 16, sa, sb, sc, sd);
#pragma unroll
      for (int b = 0; b < 16; ++b) dot[b] = fmaf(sa[b], kv.x, dot[b]);
#pragma unroll
      for (int b = 0; b < 16; ++b) dot[b] = fmaf(sb[b], kv.y, dot[b]);
#pragma unroll
      for (int b = 0; b < 16; ++b) dot[b] = fmaf(sc[b], kv.z, dot[b]);
#pragma unroll
      for (int b = 0; b < 16; ++b) dot[b] = fmaf(sd[b], kv.w, dot[b]);
    }
  }

#pragma unroll
  for (int b = 0; b < 16; ++b) {
    float v = adj[(size_t)b * 262144 + rid] * fast_sin(dot[b]);
#pragma unroll
    for (int off = 32; off > 0; off >>= 1) v += __shfl_down(v, off, 64);
    if ((t & 63) == 0) part[(t >> 6) * 16 + b] = v;
  }
  __syncthreads();
  if (t < 16) {
    float ssum = part[t] + part[16 + t] + part[32 + t] + part[48 + t];
    aggp[half * 8192 + t * 512 + l] = ssum;
  }
}

extern "C" void kernel_launch(void* const* d_in, const int* in_sizes, int n_in,
                              void* d_out, int out_size, void* d_ws, size_t ws_size,
                              hipStream_t stream) {
  const float* y0   = (const float*)d_in[0];  // [16,512]
  const float* bias = (const float*)d_in[1];  // [16,512,1]
  const float* adj  = (const float*)d_in[2];  // [16,512,512]
  const float* k0   = (const float*)d_in[3];  // [128,512,512]
  const float* k1   = (const float*)d_in[4];  // [128,512,128]
  const float* k2   = (const float*)d_in[5];  // [512,512,128]
  float* out = (float*)d_out;                 // [8,16,512] f32

  float* w      = (float*)d_ws;
  float* K0p    = w;               // 131072 floats (2 partials)
  float* K1s    = w + 131072;      // 16384
  float* M      = w + 147456;      // 65536
  float* s2T    = w + 212992;      // 2048  ([128][16] transposed)
  float* ybuf   = w + 215040;      // 16384 (2 x 8192, ping-pong)
  float* racc   = w + 231424;      // 8192
  float* aggp   = w + 239616;      // 16384 (2 halves x [16][512])
  float* rowinv = w + 256000;      // 262144 floats = 1 MB
  short* kq     = (short*)(w + 518144);  // 33554432 shorts = 64 MB
  const bool useI16 =
      ws_size >= (size_t)518144 * 4 + (size_t)33554432 * 2;

  kPrep1<<<512, 256, 0, stream>>>(k0, K0p);
  kPrep2<<<64, 256, 0, stream>>>(k1, K1s);
  kPrep3<<<256, 256, 0, stream>>>(K0p, K1s, M);
  if (useI16) kConvRow<<<16384, 256, 0, stream>>>(k2, kq, rowinv);

  // init: y = y0, s2T = (M*y0)^T  (step = -1 makes ping-pong write ybuf[0])
  kA2<<<256, 256, 0, stream>>>(y0, bias, M, aggp, ybuf, racc, s2T, out, 0, -1);

  for (int step = 0; step < 8; ++step) {
    for (int stage = 1; stage <= 4; ++stage) {
      if (useI16)
        kBi16<<<1024, 256, 0, stream>>>(kq, adj, s2T, rowinv, aggp);
      else
        kBf32<<<1024, 256, 0, stream>>>(k2, adj, s2T, aggp);
      kA2<<<256, 256, 0, stream>>>(y0, bias, M, aggp, ybuf, racc, s2T, out, stage, step);
    }
  }
}

// Round 16
// 850.812 us; speedup vs baseline: 10.5384x; 1.2145x over previous
//
#include <hip/hip_runtime.h>
#include <hip/hip_bf16.h>

typedef int int4v __attribute__((ext_vector_type(4)));
typedef long long i64;
typedef unsigned long long u64;
typedef unsigned int u32;

#define DT 0.01f

// sin(x) with Cody-Waite reduction mod pi, accurate to ~2e-7 for |x| < ~6000.
__device__ __forceinline__ float fast_sin(float x) {
  const float INVPI = 0.3183098861837907f;
  float n = rintf(x * INVPI);
  int ni = (int)n;
  float r = fmaf(n, -3.140625f, x);
  r = fmaf(n, -9.6765358979e-4f, r);
  float s = r * r;
  float p = fmaf(s, -2.5052108e-8f, 2.7557319e-6f);
  p = fmaf(s, p, -1.9841270e-4f);
  p = fmaf(s, p, 8.3333333e-3f);
  p = fmaf(s, p, -1.6666667e-1f);
  float res = fmaf(r * s, p, r);
  return (ni & 1) ? -res : res;
}

typedef float f32x16 __attribute__((ext_vector_type(16)));
// (kept for the fp32 fallback kernel)
__device__ __forceinline__ void sload4(const float* p, f32x16& a, f32x16& b,
                                       f32x16& c, f32x16& d) {
  asm volatile(
      "s_load_dwordx16 %0, %4, 0\n\t"
      "s_load_dwordx16 %1, %4, 0x40\n\t"
      "s_load_dwordx16 %2, %4, 0x80\n\t"
      "s_load_dwordx16 %3, %4, 0xc0\n\t"
      "s_waitcnt lgkmcnt(0)"
      : "=s"(a), "=s"(b), "=s"(c), "=s"(d)
      : "s"(p));
}

// K0 partial column sums (m split in 2 halves for occupancy).
__global__ __launch_bounds__(256) void kPrep1(const float* __restrict__ k0,
                                              float* __restrict__ K0p) {
  const int id = (blockIdx.x & 255) * 256 + threadIdx.x;
  const int p = blockIdx.x >> 8;
  const int h = id >> 9, j = id & 511;
  const float* q = k0 + (size_t)h * 262144 + (size_t)(p * 256) * 512 + j;
  float s = 0.f;
  for (int m = 0; m < 256; ++m) s += q[(size_t)m * 512];
  K0p[p * 65536 + id] = s;
}

// K1s[h,j] = sum_m k1[h,m,j]
__global__ __launch_bounds__(256) void kPrep2(const float* __restrict__ k1,
                                              float* __restrict__ K1s) {
  int t = blockIdx.x * 256 + threadIdx.x;
  int h = t >> 7, j = t & 127;
  const float* p = k1 + (size_t)h * 65536 + j;
  float s = 0.f;
  for (int m = 0; m < 512; ++m) s += p[(size_t)m * 128];
  K1s[t] = s;
}

// M[l,j] = sum_h K1s[l,h] * (K0pA[h,j] + K0pB[h,j])
__global__ __launch_bounds__(256) void kPrep3(const float* __restrict__ K0p,
                                              const float* __restrict__ K1s,
                                              float* __restrict__ M) {
  int t = blockIdx.x * 256 + threadIdx.x;
  int l = t >> 9, j = t & 511;
  float s = 0.f;
#pragma unroll 8
  for (int h = 0; h < 128; ++h)
    s = fmaf(K1s[l * 128 + h], K0p[h * 512 + j] + K0p[65536 + h * 512 + j], s);
  M[t] = s;
}

// Per-row int16 quantization of k2 into TWO i8 planes (hi, centered-lo):
// q = rint(k2*32767/rowmax) = 256*kh + (kl+128). Note 32767*2eps << 0.5 so
// q cannot round past 32767 (unlike the 2^23 s-quant, which needs a clamp).
// crow[row] = 32896 * sum_j(q-128).
__global__ __launch_bounds__(256) void kConvRow(const float* __restrict__ k2,
                                                signed char* __restrict__ khP,
                                                signed char* __restrict__ klP,
                                                float* __restrict__ rowinv,
                                                float* __restrict__ crow) {
  const int t = threadIdx.x;
  const int row = blockIdx.x * 16 + (t >> 4);
  const int seg = t & 15;
  const float* src = k2 + (size_t)row * 128 + seg * 8;
  const float4 a = *(const float4*)(src);
  const float4 b = *(const float4*)(src + 4);
  float m = fmaxf(fmaxf(fmaxf(fabsf(a.x), fabsf(a.y)), fmaxf(fabsf(a.z), fabsf(a.w))),
                  fmaxf(fmaxf(fabsf(b.x), fabsf(b.y)), fmaxf(fabsf(b.z), fabsf(b.w))));
#pragma unroll
  for (int off = 8; off > 0; off >>= 1) m = fmaxf(m, __shfl_xor(m, off, 64));
  const float scale = m > 0.f ? 32767.0f / m : 0.f;
  if (seg == 0) rowinv[row] = m > 0.f ? m / 32767.0f : 0.f;
  const float v[8] = {a.x, a.y, a.z, a.w, b.x, b.y, b.z, b.w};
  u64 ph = 0, pl = 0;
  int csum = 0;
#pragma unroll
  for (int i = 0; i < 8; ++i) {
    const int q = (int)rintf(v[i] * scale);
    const int kh = q >> 8;
    const int kl = (q & 255) - 128;
    ph |= (u64)(unsigned char)(signed char)kh << (8 * i);
    pl |= (u64)(unsigned char)(signed char)kl << (8 * i);
    csum += q - 128;
  }
  ((u64*)khP)[(size_t)row * 16 + seg] = ph;
  ((u64*)klP)[(size_t)row * 16 + seg] = pl;
#pragma unroll
  for (int off = 8; off > 0; off >>= 1) csum += __shfl_xor(csum, off, 64);
  if (seg == 0) crow[row] = 32896.f * (float)csum;
}

// Kernel A v2: RK4 bookkeeping + s2T = transpose(M * y_stage). (unchanged)
__global__ __launch_bounds__(256) void kA2(
    const float* __restrict__ y0, const float* __restrict__ bias,
    const float* __restrict__ M, const float* __restrict__ aggp,
    float* __restrict__ ybuf, float* __restrict__ racc,
    float* __restrict__ s2T, float* __restrict__ out,
    int stage, int step) {
  __shared__ float ystage[512];
  const int b = blockIdx.x >> 4, lg = blockIdx.x & 15, t = threadIdx.x;
  const float* ycur = ybuf + (step & 1) * 8192;
  float* ynext = ybuf + ((step + 1) & 1) * 8192;

  for (int i = t; i < 512; i += 256) {
    const int idx = b * 512 + i;
    const bool own = (i >> 5) == lg;
    float ys;
    if (stage == 0) {
      ys = y0[idx];
      if (own) ynext[idx] = ys;
    } else {
      const float r = bias[idx] - (aggp[idx] + aggp[8192 + idx]);
      const float yb = ycur[idx];
      if (stage == 1) {
        ys = fmaf(0.5f * DT, r, yb);
        if (own) racc[idx] = r;
      } else if (stage == 2) {
        ys = fmaf(0.5f * DT, r, yb);
        if (own) racc[idx] = racc[idx] + 2.f * r;
      } else if (stage == 3) {
        ys = fmaf(DT, r, yb);
        if (own) racc[idx] = racc[idx] + 2.f * r;
      } else {
        ys = yb + (DT / 6.f) * (racc[idx] + r);
        if (own) { ynext[idx] = ys; out[step * 8192 + idx] = ys; }
      }
    }
    ystage[i] = ys;
  }
  __syncthreads();

  const int g = t >> 5, u = t & 31;
  const int l = lg * 8 + g;
  const float* Mrow = M + l * 512;
  const int i0 = u * 16;
  float p = 0.f;
#pragma unroll
  for (int k = 0; k < 4; ++k) {
    const int off = ((u + k) & 3) << 2;
    const float4 mv = *(const float4*)(Mrow + i0 + off);
    const float4 yv = *(const float4*)(ystage + i0 + off);
    p = fmaf(mv.x, yv.x, p);
    p = fmaf(mv.y, yv.y, p);
    p = fmaf(mv.z, yv.z, p);
    p = fmaf(mv.w, yv.w, p);
  }
#pragma unroll
  for (int off = 16; off > 0; off >>= 1) p += __shfl_down(p, off, 32);
  if (u == 0) s2T[l * 16 + b] = p;
}

// Kernel B (i8 MFMA): dot[rid,b] via exact integer GEMM decomposition.
//   qk = 256*kh + (kl+128); qs = 65536*sh + 256*(sm+128) + (sl+128)
//   sum_j qk*qs = 2^24*Ga + 2^16*Gb + 2^8*Gc + Gd + crow + cb   (int-exact)
// FIX vs R15: clamp q_s to +/-8388607 — at 2^23 scale, fp32 rounding can
// push rint to 8388608 whose high byte (128) wraps to -128 in i8, flipping
// the sign of the max s2 element per batch (the R15 absmax=1.695 bug).
// Layouts (AMD frag maps + m89-verified C/D): A row=lane&15, B col=lane&15,
// D col=lane&15 / row=(lane>>4)*4+reg; k-permutations cancel between A and B.
__global__ __launch_bounds__(256) void kBi8(
    const signed char* __restrict__ khP, const signed char* __restrict__ klP,
    const float* __restrict__ adj, const float* __restrict__ s2T,
    const float* __restrict__ rowinv, const float* __restrict__ crow,
    float* __restrict__ aggp) {
  __shared__ __align__(8) signed char sqA[16][136];  // sh plane, [b][k]
  __shared__ __align__(8) signed char sqB[16][136];  // sm
  __shared__ __align__(8) signed char sqC[16][136];  // sl
  __shared__ float sred[16][16];
  __shared__ float scaleL[16], sinvLs[16], cbLs[16];
  __shared__ float part[64];
  const int t = threadIdx.x;
  const int b16 = t & 15, jg = t >> 4;

  // phase 1: per-b absmax of s2T[j][b]
  float mx = 0.f;
#pragma unroll
  for (int i = 0; i < 8; ++i)
    mx = fmaxf(mx, fabsf(s2T[(jg * 8 + i) * 16 + b16]));
  sred[jg][b16] = mx;
  __syncthreads();
  if (t < 16) {
    float m = 0.f;
#pragma unroll
    for (int g = 0; g < 16; ++g) m = fmaxf(m, sred[g][t]);
    scaleL[t] = m > 0.f ? 8388607.f / m : 0.f;
    sinvLs[t] = m > 0.f ? m / 8388607.f : 0.f;
  }
  __syncthreads();
  // phase 2: quantize s to 3 i8 planes (transposed [b][k]) + cb partials
  {
    const float sc = scaleL[b16];
    u64 pa = 0, pb = 0, pc = 0;
    int ps2 = 0, psm = 0, psl = 0;
#pragma unroll
    for (int i = 0; i < 8; ++i) {
      int q = (int)rintf(s2T[(jg * 8 + i) * 16 + b16] * sc);
      q = q > 8388607 ? 8388607 : (q < -8388607 ? -8388607 : q);  // THE FIX
      const int h = q >> 16;
      const int m = ((q >> 8) & 255) - 128;
      const int lo = (q & 255) - 128;
      pa |= (u64)(unsigned char)(signed char)h << (8 * i);
      pb |= (u64)(unsigned char)(signed char)m << (8 * i);
      pc |= (u64)(unsigned char)(signed char)lo << (8 * i);
      ps2 += h; psm += m; psl += lo;
    }
    *(u64*)&sqA[b16][jg * 8] = pa;
    *(u64*)&sqB[b16][jg * 8] = pb;
    *(u64*)&sqC[b16][jg * 8] = pc;
    sred[jg][b16] = 8388608.f * (float)ps2 + 32768.f * (float)psm + 128.f * (float)psl;
  }
  __syncthreads();
  if (t < 16) {
    float s = 0.f;
#pragma unroll
    for (int g = 0; g < 16; ++g) s += sred[g][t];
    cbLs[t] = s + 538968064.f;   // + 128*32896*K (K=128)
  }
  __syncthreads();

  // B fragments: lane (b=lane&15, kg=lane>>4) holds 8 k-bytes per chunk.
  const int lane = t & 63, w = t >> 6;
  const int bb = lane & 15, kg = lane >> 4;
  i64 bA[4], bB[4], bC[4];
#pragma unroll
  for (int c = 0; c < 4; ++c) {
    const int kb = c * 32 + kg * 8;
    bA[c] = *(const i64*)&sqA[bb][kb];
    bB[c] = *(const i64*)&sqB[bb][kb];
    bC[c] = *(const i64*)&sqC[bb][kb];
  }
  const float sb = sinvLs[bb], cbb = cbLs[bb];

  const int rid0 = blockIdx.x * 256;
  const int l = rid0 >> 9;
  const int half = blockIdx.x & 1;
  const i64* khL = (const i64*)khP;
  const i64* klL = (const i64*)klP;

  float bacc = 0.f;
#pragma unroll
  for (int tt = 0; tt < 4; ++tt) {
    const int ridT = rid0 + w * 64 + tt * 16;
    const int rowA = ridT + bb;   // A-frag: row = lane&15
    i64 ah[4], al[4];
#pragma unroll
    for (int c = 0; c < 4; ++c) {
      ah[c] = khL[(size_t)rowA * 16 + c * 4 + kg];
      al[c] = klL[(size_t)rowA * 16 + c * 4 + kg];
    }
    int4v Ga = {0, 0, 0, 0}, Gb = {0, 0, 0, 0}, Gc = {0, 0, 0, 0}, Gd = {0, 0, 0, 0};
#pragma unroll
    for (int c = 0; c < 4; ++c) {
      Ga = __builtin_amdgcn_mfma_i32_16x16x32_i8(ah[c], bA[c], Ga, 0, 0, 0);
      Gb = __builtin_amdgcn_mfma_i32_16x16x32_i8(ah[c], bB[c], Gb, 0, 0, 0);
      Gb = __builtin_amdgcn_mfma_i32_16x16x32_i8(al[c], bA[c], Gb, 0, 0, 0);
      Gc = __builtin_amdgcn_mfma_i32_16x16x32_i8(ah[c], bC[c], Gc, 0, 0, 0);
      Gc = __builtin_amdgcn_mfma_i32_16x16x32_i8(al[c], bB[c], Gc, 0, 0, 0);
      Gd = __builtin_amdgcn_mfma_i32_16x16x32_i8(al[c], bC[c], Gd, 0, 0, 0);
    }
    // epilogue: C/D row = kg*4 + reg, col = bb (verified layout)
    const int rbase = ridT + kg * 4;
    const float4 cr = *(const float4*)(crow + rbase);
    const float4 ri = *(const float4*)(rowinv + rbase);
    const float4 ad = *(const float4*)(adj + (size_t)bb * 262144 + rbase);
    const float crA[4] = {cr.x, cr.y, cr.z, cr.w};
    const float riA[4] = {ri.x, ri.y, ri.z, ri.w};
    const float adA[4] = {ad.x, ad.y, ad.z, ad.w};
    float ts = 0.f;
#pragma unroll
    for (int r = 0; r < 4; ++r) {
      const float dq = 16777216.f * (float)Ga[r] + 65536.f * (float)Gb[r] +
                       256.f * (float)Gc[r] + (float)Gd[r] + crA[r] + cbb;
      ts += adA[r] * fast_sin(dq * (riA[r] * sb));
    }
    ts += __shfl_xor(ts, 16, 64);
    ts += __shfl_xor(ts, 32, 64);
    bacc += ts;   // all lanes hold tile-sum for their b
  }
  if (lane < 16) part[w * 16 + lane] = bacc;
  __syncthreads();
  if (t < 16) {
    float ssum = part[t] + part[16 + t] + part[32 + t] + part[48 + t];
    aggp[half * 8192 + t * 512 + l] = ssum;   // aggp[half][b][l]
  }
}

// Kernel B fallback (fp32 k2, R4 body) — only if ws_size can't hold planes.
__global__ __launch_bounds__(256) void kBf32(
    const float* __restrict__ k2, const float* __restrict__ adj,
    const float* __restrict__ s2T, float* __restrict__ aggp) {
  __shared__ float lk[256 * 36];
  __shared__ float part[64];
  const int t = threadIdx.x;
  const int rid0 = blockIdx.x * 256;
  const int rid = rid0 + t;
  const int l = rid0 >> 9;
  const int half = blockIdx.x & 1;

  float dot[16];
#pragma unroll
  for (int b = 0; b < 16; ++b) dot[b] = 0.f;

  for (int c = 0; c < 4; ++c) {
    __syncthreads();
#pragma unroll
    for (int k = 0; k < 8; ++k) {
      const int f = k * 256 + t, row = f >> 3, e = f & 7;
      const float4 v = *(const float4*)(k2 + (size_t)(rid0 + row) * 128 + c * 32 + e * 4);
      *(float4*)(lk + row * 36 + e * 4) = v;
    }
    __syncthreads();
    const float* myrow = lk + t * 36;
#pragma unroll
    for (int q = 0; q < 8; ++q) {
      const float4 kv = *(const float4*)(myrow + q * 4);
      f32x16 sa, sb, sc, sd;
      sload4(s2T + (c * 32 + q * 4) * 16, sa, sb, sc, sd);
#pragma unroll
      for (int b = 0; b < 16; ++b) dot[b] = fmaf(sa[b], kv.x, dot[b]);
#pragma unroll
      for (int b = 0; b < 16; ++b) dot[b] = fmaf(sb[b], kv.y, dot[b]);
#pragma unroll
      for (int b = 0; b < 16; ++b) dot[b] = fmaf(sc[b], kv.z, dot[b]);
#pragma unroll
      for (int b = 0; b < 16; ++b) dot[b] = fmaf(sd[b], kv.w, dot[b]);
    }
  }

#pragma unroll
  for (int b = 0; b < 16; ++b) {
    float v = adj[(size_t)b * 262144 + rid] * fast_sin(dot[b]);
#pragma unroll
    for (int off = 32; off > 0; off >>= 1) v += __shfl_down(v, off, 64);
    if ((t & 63) == 0) part[(t >> 6) * 16 + b] = v;
  }
  __syncthreads();
  if (t < 16) {
    float ssum = part[t] + part[16 + t] + part[32 + t] + part[48 + t];
    aggp[half * 8192 + t * 512 + l] = ssum;
  }
}

extern "C" void kernel_launch(void* const* d_in, const int* in_sizes, int n_in,
                              void* d_out, int out_size, void* d_ws, size_t ws_size,
                              hipStream_t stream) {
  const float* y0   = (const float*)d_in[0];  // [16,512]
  const float* bias = (const float*)d_in[1];  // [16,512,1]
  const float* adj  = (const float*)d_in[2];  // [16,512,512]
  const float* k0   = (const float*)d_in[3];  // [128,512,512]
  const float* k1   = (const float*)d_in[4];  // [128,512,128]
  const float* k2   = (const float*)d_in[5];  // [512,512,128]
  float* out = (float*)d_out;                 // [8,16,512] f32

  float* w      = (float*)d_ws;
  float* K0p    = w;               // 131072 floats
  float* K1s    = w + 131072;      // 16384
  float* M      = w + 147456;      // 65536
  float* s2T    = w + 212992;      // 2048
  float* ybuf   = w + 215040;      // 16384
  float* racc   = w + 231424;      // 8192
  float* aggp   = w + 239616;      // 16384
  float* rowinv = w + 256000;      // 262144
  float* crow   = w + 518144;      // 262144
  signed char* khP = (signed char*)(w + 780288);   // 32 MB
  signed char* klP = khP + 33554432;               // 32 MB
  const bool useI8 =
      ws_size >= (size_t)780288 * 4 + (size_t)2 * 33554432;

  kPrep1<<<512, 256, 0, stream>>>(k0, K0p);
  kPrep2<<<64, 256, 0, stream>>>(k1, K1s);
  kPrep3<<<256, 256, 0, stream>>>(K0p, K1s, M);
  if (useI8) kConvRow<<<16384, 256, 0, stream>>>(k2, khP, klP, rowinv, crow);

  kA2<<<256, 256, 0, stream>>>(y0, bias, M, aggp, ybuf, racc, s2T, out, 0, -1);

  for (int step = 0; step < 8; ++step) {
    for (int stage = 1; stage <= 4; ++stage) {
      if (useI8)
        kBi8<<<1024, 256, 0, stream>>>(khP, klP, adj, s2T, rowinv, crow, aggp);
      else
        kBf32<<<1024, 256, 0, stream>>>(k2, adj, s2T, aggp);
      kA2<<<256, 256, 0, stream>>>(y0, bias, M, aggp, ybuf, racc, s2T, out, stage, step);
    }
  }
}

// Round 17
// 770.910 us; speedup vs baseline: 11.6306x; 1.1036x over previous
//
#include <hip/hip_runtime.h>
#include <hip/hip_bf16.h>

typedef int int4v __attribute__((ext_vector_type(4)));
typedef long long i64;
typedef long long i64x2 __attribute__((ext_vector_type(2)));
typedef unsigned long long u64;
typedef unsigned int u32;

#define DT 0.01f

// sin(x) with Cody-Waite reduction mod pi, accurate to ~2e-7 for |x| < ~6000.
__device__ __forceinline__ float fast_sin(float x) {
  const float INVPI = 0.3183098861837907f;
  float n = rintf(x * INVPI);
  int ni = (int)n;
  float r = fmaf(n, -3.140625f, x);
  r = fmaf(n, -9.6765358979e-4f, r);
  float s = r * r;
  float p = fmaf(s, -2.5052108e-8f, 2.7557319e-6f);
  p = fmaf(s, p, -1.9841270e-4f);
  p = fmaf(s, p, 8.3333333e-3f);
  p = fmaf(s, p, -1.6666667e-1f);
  float res = fmaf(r * s, p, r);
  return (ni & 1) ? -res : res;
}

typedef float f32x16 __attribute__((ext_vector_type(16)));
// (kept for the fp32 fallback kernel)
__device__ __forceinline__ void sload4(const float* p, f32x16& a, f32x16& b,
                                       f32x16& c, f32x16& d) {
  asm volatile(
      "s_load_dwordx16 %0, %4, 0\n\t"
      "s_load_dwordx16 %1, %4, 0x40\n\t"
      "s_load_dwordx16 %2, %4, 0x80\n\t"
      "s_load_dwordx16 %3, %4, 0xc0\n\t"
      "s_waitcnt lgkmcnt(0)"
      : "=s"(a), "=s"(b), "=s"(c), "=s"(d)
      : "s"(p));
}

// K0 partial column sums (m split in 2 halves for occupancy).
__global__ __launch_bounds__(256) void kPrep1(const float* __restrict__ k0,
                                              float* __restrict__ K0p) {
  const int id = (blockIdx.x & 255) * 256 + threadIdx.x;
  const int p = blockIdx.x >> 8;
  const int h = id >> 9, j = id & 511;
  const float* q = k0 + (size_t)h * 262144 + (size_t)(p * 256) * 512 + j;
  float s = 0.f;
  for (int m = 0; m < 256; ++m) s += q[(size_t)m * 512];
  K0p[p * 65536 + id] = s;
}

// K1s[h,j] = sum_m k1[h,m,j]
__global__ __launch_bounds__(256) void kPrep2(const float* __restrict__ k1,
                                              float* __restrict__ K1s) {
  int t = blockIdx.x * 256 + threadIdx.x;
  int h = t >> 7, j = t & 127;
  const float* p = k1 + (size_t)h * 65536 + j;
  float s = 0.f;
  for (int m = 0; m < 512; ++m) s += p[(size_t)m * 128];
  K1s[t] = s;
}

// M[l,j] = sum_h K1s[l,h] * (K0pA[h,j] + K0pB[h,j])
__global__ __launch_bounds__(256) void kPrep3(const float* __restrict__ K0p,
                                              const float* __restrict__ K1s,
                                              float* __restrict__ M) {
  int t = blockIdx.x * 256 + threadIdx.x;
  int l = t >> 9, j = t & 511;
  float s = 0.f;
#pragma unroll 8
  for (int h = 0; h < 128; ++h)
    s = fmaf(K1s[l * 128 + h], K0p[h * 512 + j] + K0p[65536 + h * 512 + j], s);
  M[t] = s;
}

// Per-row int16 quantization of k2 into interleaved i8 planes stored in
// MFMA FRAGMENT ORDER: kF[tile][c][lane] = {kh_8bytes, kl_8bytes}, 16B/lane
// (tile = row>>4, c = seg>>2, lane = (seg&3)*16 + (row&15)). kBi8's per-
// (tile,c) A-frag load is then one coalesced 1024B wave-load. Writes here
// are scattered 16B (one-time, L2-absorbed). q cannot round past 32767
// (32767*2eps << 0.5) so no clamp needed on the k side.
__global__ __launch_bounds__(256) void kConvRow(const float* __restrict__ k2,
                                                i64x2* __restrict__ kF2,
                                                float* __restrict__ rowinv,
                                                float* __restrict__ crow) {
  const int t = threadIdx.x;
  const int row = blockIdx.x * 16 + (t >> 4);
  const int seg = t & 15;
  const float* src = k2 + (size_t)row * 128 + seg * 8;
  const float4 a = *(const float4*)(src);
  const float4 b = *(const float4*)(src + 4);
  float m = fmaxf(fmaxf(fmaxf(fabsf(a.x), fabsf(a.y)), fmaxf(fabsf(a.z), fabsf(a.w))),
                  fmaxf(fmaxf(fabsf(b.x), fabsf(b.y)), fmaxf(fabsf(b.z), fabsf(b.w))));
#pragma unroll
  for (int off = 8; off > 0; off >>= 1) m = fmaxf(m, __shfl_xor(m, off, 64));
  const float scale = m > 0.f ? 32767.0f / m : 0.f;
  if (seg == 0) rowinv[row] = m > 0.f ? m / 32767.0f : 0.f;
  const float v[8] = {a.x, a.y, a.z, a.w, b.x, b.y, b.z, b.w};
  u64 ph = 0, pl = 0;
  int csum = 0;
#pragma unroll
  for (int i = 0; i < 8; ++i) {
    const int q = (int)rintf(v[i] * scale);
    const int kh = q >> 8;
    const int kl = (q & 255) - 128;
    ph |= (u64)(unsigned char)(signed char)kh << (8 * i);
    pl |= (u64)(unsigned char)(signed char)kl << (8 * i);
    csum += q - 128;
  }
  // fragment-order index: ((row>>4)*4 + (seg>>2))*64 + (seg&3)*16 + (row&15)
  i64x2 wv;
  wv.x = (i64)ph;
  wv.y = (i64)pl;
  kF2[((size_t)(row >> 4) * 4 + (seg >> 2)) * 64 + (seg & 3) * 16 + (row & 15)] = wv;
#pragma unroll
  for (int off = 8; off > 0; off >>= 1) csum += __shfl_xor(csum, off, 64);
  if (seg == 0) crow[row] = 32896.f * (float)csum;
}

// Kernel A v2: RK4 bookkeeping + s2T = transpose(M * y_stage). (unchanged)
__global__ __launch_bounds__(256) void kA2(
    const float* __restrict__ y0, const float* __restrict__ bias,
    const float* __restrict__ M, const float* __restrict__ aggp,
    float* __restrict__ ybuf, float* __restrict__ racc,
    float* __restrict__ s2T, float* __restrict__ out,
    int stage, int step) {
  __shared__ float ystage[512];
  const int b = blockIdx.x >> 4, lg = blockIdx.x & 15, t = threadIdx.x;
  const float* ycur = ybuf + (step & 1) * 8192;
  float* ynext = ybuf + ((step + 1) & 1) * 8192;

  for (int i = t; i < 512; i += 256) {
    const int idx = b * 512 + i;
    const bool own = (i >> 5) == lg;
    float ys;
    if (stage == 0) {
      ys = y0[idx];
      if (own) ynext[idx] = ys;
    } else {
      const float r = bias[idx] - (aggp[idx] + aggp[8192 + idx]);
      const float yb = ycur[idx];
      if (stage == 1) {
        ys = fmaf(0.5f * DT, r, yb);
        if (own) racc[idx] = r;
      } else if (stage == 2) {
        ys = fmaf(0.5f * DT, r, yb);
        if (own) racc[idx] = racc[idx] + 2.f * r;
      } else if (stage == 3) {
        ys = fmaf(DT, r, yb);
        if (own) racc[idx] = racc[idx] + 2.f * r;
      } else {
        ys = yb + (DT / 6.f) * (racc[idx] + r);
        if (own) { ynext[idx] = ys; out[step * 8192 + idx] = ys; }
      }
    }
    ystage[i] = ys;
  }
  __syncthreads();

  const int g = t >> 5, u = t & 31;
  const int l = lg * 8 + g;
  const float* Mrow = M + l * 512;
  const int i0 = u * 16;
  float p = 0.f;
#pragma unroll
  for (int k = 0; k < 4; ++k) {
    const int off = ((u + k) & 3) << 2;
    const float4 mv = *(const float4*)(Mrow + i0 + off);
    const float4 yv = *(const float4*)(ystage + i0 + off);
    p = fmaf(mv.x, yv.x, p);
    p = fmaf(mv.y, yv.y, p);
    p = fmaf(mv.z, yv.z, p);
    p = fmaf(mv.w, yv.w, p);
  }
#pragma unroll
  for (int off = 16; off > 0; off >>= 1) p += __shfl_down(p, off, 32);
  if (u == 0) s2T[l * 16 + b] = p;
}

// Kernel B (i8 MFMA, fragment-order k planes): dot[rid,b] via exact integer
// GEMM decomposition (see R16). A-frag loads are now ONE dwordx4 per
// (tile,c) at lane-consecutive addresses (1024B/wave-load) — both planes in
// one load. Math byte-identical to R16 (absmax 0.05273438).
__global__ __launch_bounds__(256) void kBi8(
    const i64x2* __restrict__ kF2,
    const float* __restrict__ adj, const float* __restrict__ s2T,
    const float* __restrict__ rowinv, const float* __restrict__ crow,
    float* __restrict__ aggp) {
  __shared__ __align__(8) signed char sqA[16][136];  // sh plane, [b][k]
  __shared__ __align__(8) signed char sqB[16][136];  // sm
  __shared__ __align__(8) signed char sqC[16][136];  // sl
  __shared__ float sred[16][16];
  __shared__ float scaleL[16], sinvLs[16], cbLs[16];
  __shared__ float part[64];
  const int t = threadIdx.x;
  const int b16 = t & 15, jg = t >> 4;

  // phase 1: per-b absmax of s2T[j][b]
  float mx = 0.f;
#pragma unroll
  for (int i = 0; i < 8; ++i)
    mx = fmaxf(mx, fabsf(s2T[(jg * 8 + i) * 16 + b16]));
  sred[jg][b16] = mx;
  __syncthreads();
  if (t < 16) {
    float m = 0.f;
#pragma unroll
    for (int g = 0; g < 16; ++g) m = fmaxf(m, sred[g][t]);
    scaleL[t] = m > 0.f ? 8388607.f / m : 0.f;
    sinvLs[t] = m > 0.f ? m / 8388607.f : 0.f;
  }
  __syncthreads();
  // phase 2: quantize s to 3 i8 planes (transposed [b][k]) + cb partials
  {
    const float sc = scaleL[b16];
    u64 pa = 0, pb = 0, pc = 0;
    int ps2 = 0, psm = 0, psl = 0;
#pragma unroll
    for (int i = 0; i < 8; ++i) {
      int q = (int)rintf(s2T[(jg * 8 + i) * 16 + b16] * sc);
      q = q > 8388607 ? 8388607 : (q < -8388607 ? -8388607 : q);  // i8 wrap guard
      const int h = q >> 16;
      const int m = ((q >> 8) & 255) - 128;
      const int lo = (q & 255) - 128;
      pa |= (u64)(unsigned char)(signed char)h << (8 * i);
      pb |= (u64)(unsigned char)(signed char)m << (8 * i);
      pc |= (u64)(unsigned char)(signed char)lo << (8 * i);
      ps2 += h; psm += m; psl += lo;
    }
    *(u64*)&sqA[b16][jg * 8] = pa;
    *(u64*)&sqB[b16][jg * 8] = pb;
    *(u64*)&sqC[b16][jg * 8] = pc;
    sred[jg][b16] = 8388608.f * (float)ps2 + 32768.f * (float)psm + 128.f * (float)psl;
  }
  __syncthreads();
  if (t < 16) {
    float s = 0.f;
#pragma unroll
    for (int g = 0; g < 16; ++g) s += sred[g][t];
    cbLs[t] = s + 538968064.f;   // + 128*32896*K (K=128)
  }
  __syncthreads();

  // B fragments: lane (b=lane&15, kg=lane>>4) holds 8 k-bytes per chunk.
  const int lane = t & 63, w = t >> 6;
  const int bb = lane & 15, kg = lane >> 4;
  i64 bA[4], bB[4], bC[4];
#pragma unroll
  for (int c = 0; c < 4; ++c) {
    const int kb = c * 32 + kg * 8;
    bA[c] = *(const i64*)&sqA[bb][kb];
    bB[c] = *(const i64*)&sqB[bb][kb];
    bC[c] = *(const i64*)&sqC[bb][kb];
  }
  const float sb = sinvLs[bb], cbb = cbLs[bb];

  const int rid0 = blockIdx.x * 256;
  const int l = rid0 >> 9;
  const int half = blockIdx.x & 1;

  float bacc = 0.f;
#pragma unroll
  for (int tt = 0; tt < 4; ++tt) {
    const int ridT = rid0 + w * 64 + tt * 16;
    const size_t tile = (size_t)(ridT >> 4);
    i64 ah[4], al[4];
#pragma unroll
    for (int c = 0; c < 4; ++c) {
      const i64x2 v = kF2[(tile * 4 + c) * 64 + lane];  // coalesced 16B/lane
      ah[c] = v.x;
      al[c] = v.y;
    }
    int4v Ga = {0, 0, 0, 0}, Gb = {0, 0, 0, 0}, Gc = {0, 0, 0, 0}, Gd = {0, 0, 0, 0};
#pragma unroll
    for (int c = 0; c < 4; ++c) {
      Ga = __builtin_amdgcn_mfma_i32_16x16x32_i8(ah[c], bA[c], Ga, 0, 0, 0);
      Gb = __builtin_amdgcn_mfma_i32_16x16x32_i8(ah[c], bB[c], Gb, 0, 0, 0);
      Gb = __builtin_amdgcn_mfma_i32_16x16x32_i8(al[c], bA[c], Gb, 0, 0, 0);
      Gc = __builtin_amdgcn_mfma_i32_16x16x32_i8(ah[c], bC[c], Gc, 0, 0, 0);
      Gc = __builtin_amdgcn_mfma_i32_16x16x32_i8(al[c], bB[c], Gc, 0, 0, 0);
      Gd = __builtin_amdgcn_mfma_i32_16x16x32_i8(al[c], bC[c], Gd, 0, 0, 0);
    }
    // epilogue: C/D row = kg*4 + reg, col = bb (verified layout)
    const int rbase = ridT + kg * 4;
    const float4 cr = *(const float4*)(crow + rbase);
    const float4 ri = *(const float4*)(rowinv + rbase);
    const float4 ad = *(const float4*)(adj + (size_t)bb * 262144 + rbase);
    const float crA[4] = {cr.x, cr.y, cr.z, cr.w};
    const float riA[4] = {ri.x, ri.y, ri.z, ri.w};
    const float adA[4] = {ad.x, ad.y, ad.z, ad.w};
    float ts = 0.f;
#pragma unroll
    for (int r = 0; r < 4; ++r) {
      const float dq = 16777216.f * (float)Ga[r] + 65536.f * (float)Gb[r] +
                       256.f * (float)Gc[r] + (float)Gd[r] + crA[r] + cbb;
      ts += adA[r] * fast_sin(dq * (riA[r] * sb));
    }
    ts += __shfl_xor(ts, 16, 64);
    ts += __shfl_xor(ts, 32, 64);
    bacc += ts;   // all lanes hold tile-sum for their b
  }
  if (lane < 16) part[w * 16 + lane] = bacc;
  __syncthreads();
  if (t < 16) {
    float ssum = part[t] + part[16 + t] + part[32 + t] + part[48 + t];
    aggp[half * 8192 + t * 512 + l] = ssum;   // aggp[half][b][l]
  }
}

// Kernel B fallback (fp32 k2, R4 body) — only if ws_size can't hold planes.
__global__ __launch_bounds__(256) void kBf32(
    const float* __restrict__ k2, const float* __restrict__ adj,
    const float* __restrict__ s2T, float* __restrict__ aggp) {
  __shared__ float lk[256 * 36];
  __shared__ float part[64];
  const int t = threadIdx.x;
  const int rid0 = blockIdx.x * 256;
  const int rid = rid0 + t;
  const int l = rid0 >> 9;
  const int half = blockIdx.x & 1;

  float dot[16];
#pragma unroll
  for (int b = 0; b < 16; ++b) dot[b] = 0.f;

  for (int c = 0; c < 4; ++c) {
    __syncthreads();
#pragma unroll
    for (int k = 0; k < 8; ++k) {
      const int f = k * 256 + t, row = f >> 3, e = f & 7;
      const float4 v = *(const float4*)(k2 + (size_t)(rid0 + row) * 128 + c * 32 + e * 4);
      *(float4*)(lk + row * 36 + e * 4) = v;
    }
    __syncthreads();
    const float* myrow = lk + t * 36;
#pragma unroll
    for (int q = 0; q < 8; ++q) {
      const float4 kv = *(const float4*)(myrow + q * 4);
      f32x16 sa, sb, sc, sd;
      sload4(s2T + (c * 32 + q * 4) * 16, sa, sb, sc, sd);
#pragma unroll
      for (int b = 0; b < 16; ++b) dot[b] = fmaf(sa[b], kv.x, dot[b]);
#pragma unroll
      for (int b = 0; b < 16; ++b) dot[b] = fmaf(sb[b], kv.y, dot[b]);
#pragma unroll
      for (int b = 0; b < 16; ++b) dot[b] = fmaf(sc[b], kv.z, dot[b]);
#pragma unroll
      for (int b = 0; b < 16; ++b) dot[b] = fmaf(sd[b], kv.w, dot[b]);
    }
  }

#pragma unroll
  for (int b = 0; b < 16; ++b) {
    float v = adj[(size_t)b * 262144 + rid] * fast_sin(dot[b]);
#pragma unroll
    for (int off = 32; off > 0; off >>= 1) v += __shfl_down(v, off, 64);
    if ((t & 63) == 0) part[(t >> 6) * 16 + b] = v;
  }
  __syncthreads();
  if (t < 16) {
    float ssum = part[t] + part[16 + t] + part[32 + t] + part[48 + t];
    aggp[half * 8192 + t * 512 + l] = ssum;
  }
}

extern "C" void kernel_launch(void* const* d_in, const int* in_sizes, int n_in,
                              void* d_out, int out_size, void* d_ws, size_t ws_size,
                              hipStream_t stream) {
  const float* y0   = (const float*)d_in[0];  // [16,512]
  const float* bias = (const float*)d_in[1];  // [16,512,1]
  const float* adj  = (const float*)d_in[2];  // [16,512,512]
  const float* k0   = (const float*)d_in[3];  // [128,512,512]
  const float* k1   = (const float*)d_in[4];  // [128,512,128]
  const float* k2   = (const float*)d_in[5];  // [512,512,128]
  float* out = (float*)d_out;                 // [8,16,512] f32

  float* w      = (float*)d_ws;
  float* K0p    = w;               // 131072 floats
  float* K1s    = w + 131072;      // 16384
  float* M      = w + 147456;      // 65536
  float* s2T    = w + 212992;      // 2048
  float* ybuf   = w + 215040;      // 16384
  float* racc   = w + 231424;      // 8192
  float* aggp   = w + 239616;      // 16384
  float* rowinv = w + 256000;      // 262144
  float* crow   = w + 518144;      // 262144
  i64x2* kF2    = (i64x2*)(w + 780288);   // 64 MB interleaved i8 planes
  const bool useI8 =
      ws_size >= (size_t)780288 * 4 + (size_t)2 * 33554432;

  kPrep1<<<512, 256, 0, stream>>>(k0, K0p);
  kPrep2<<<64, 256, 0, stream>>>(k1, K1s);
  kPrep3<<<256, 256, 0, stream>>>(K0p, K1s, M);
  if (useI8) kConvRow<<<16384, 256, 0, stream>>>(k2, kF2, rowinv, crow);

  kA2<<<256, 256, 0, stream>>>(y0, bias, M, aggp, ybuf, racc, s2T, out, 0, -1);

  for (int step = 0; step < 8; ++step) {
    for (int stage = 1; stage <= 4; ++stage) {
      if (useI8)
        kBi8<<<1024, 256, 0, stream>>>(kF2, adj, s2T, rowinv, crow, aggp);
      else
        kBf32<<<1024, 256, 0, stream>>>(k2, adj, s2T, aggp);
      kA2<<<256, 256, 0, stream>>>(y0, bias, M, aggp, ybuf, racc, s2T, out, stage, step);
    }
  }
}